// Round 7
// baseline (515.540 us; speedup 1.0000x reference)
//
#include <hip/hip_runtime.h>

typedef _Float16 f16_t;
typedef _Float16 f16x4 __attribute__((ext_vector_type(4)));
typedef _Float16 f16x8 __attribute__((ext_vector_type(8)));
typedef short s16x8 __attribute__((ext_vector_type(8)));
typedef unsigned short u16x4 __attribute__((ext_vector_type(4)));
typedef float floatx4 __attribute__((ext_vector_type(4)));

#define NB 8
#define SEQ 1024
#define DIM 768
#define NBLK 768
// 1/sqrt(768)
#define INV_SCALE 0.03608439182435161f
// constant shift for unscaled row softmax (shift-invariant; row maxes ~35).
// e values are stored UNNORMALIZED in bf16 (fp32 exponent range -> no
// underflow for small row maxes); normalization happens in the apply epilogue.
#define ROW_SHIFT 40.0f

// float -> bf16 round-to-nearest-even
__device__ inline unsigned short f2bf(float f) {
  unsigned u = __builtin_bit_cast(unsigned, f);
  u += 0x7fffu + ((u >> 16) & 1u);
  return (unsigned short)(u >> 16);
}

// ---------------------------------------------------------------------------
// async 16B global->LDS; LDS dest = wave-uniform base + lane*16 (m104/m108).
__device__ inline void async_load16(const void* g, void* l) {
  __builtin_amdgcn_global_load_lds((__attribute__((address_space(1))) void*)g,
                                   (__attribute__((address_space(3))) void*)l,
                                   16, 0, 0);
}

// ---------------------------------------------------------------------------
// Device-scope grid barrier. Safe because all NBLK blocks are co-resident:
// __launch_bounds__(256,3) caps VGPRs for 3 blocks/CU, LDS 33.3KB allows 4,
// grid = 3*256 exactly. Each phase uses a fresh {count,flag} pair (memset to
// 0 in-stream before launch). atomicAdd/atomicOr on global are device-scope
// (m20); __threadfence = agent acq_rel fence (L2 wb + inv on gfx950) makes
// pre-barrier writes visible across XCDs — same cost a kernel boundary pays.
__device__ inline void grid_barrier(unsigned* sync, int phase) {
  __syncthreads();
  if (threadIdx.x == 0) {
    __threadfence();
    const unsigned arrived = atomicAdd(&sync[phase * 2], 1u);
    if (arrived == NBLK - 1) {
      atomicExch(&sync[phase * 2 + 1], 1u);
    } else {
      while (atomicOr(&sync[phase * 2 + 1], 0u) == 0u)
        __builtin_amdgcn_s_sleep(8);
    }
    __threadfence();
  }
  __syncthreads();
}

// ---------------------------------------------------------------------------
// Mega-kernel: prep -> proj -> scores -> apply with grid barriers between.
// Phase bodies identical to the r6 4-launch version (verified); only the
// block-index plumbing changed. Eliminates 3 launch gaps + ramp/drains.
__global__ __launch_bounds__(256, 3) void mega(
    const float* __restrict__ lhs, const float* __restrict__ rhs,
    const float* __restrict__ Wl, const float* __restrict__ Wr,
    f16_t* __restrict__ lhs_f, f16_t* __restrict__ rhs_f,
    f16_t* __restrict__ Wl_h, f16_t* __restrict__ Wr_h,
    f16_t* __restrict__ lhsT, unsigned short* __restrict__ rhsT,
    f16_t* __restrict__ l_f, f16_t* __restrict__ r_f,
    unsigned short* __restrict__ e_l, f16_t* __restrict__ e_rT,
    float* __restrict__ rowpart, float* __restrict__ colpart,
    float* __restrict__ out0, float* __restrict__ out1, unsigned* sync) {
  __shared__ __align__(16) char smem[32768];
  __shared__ __align__(16) float sinv[128];
  const int bid = blockIdx.x;
  const int tid = threadIdx.x;
  const int lane = tid & 63;
  const int wave = tid >> 6;
  const int wr = wave >> 1, wc = wave & 1;
  const int fr = lane & 15;
  const int fq = lane >> 4;
  const int swz = ((lane & 7) ^ (lane >> 3)) << 3;  // staging src column XOR
  const int x7 = (fr & 7) << 3;                     // read-side XOR

  // ===== phase 0: FAT prep (grid-strided over 3456 virtual tiles) =====
  {
    const int x4 = (tid & 15) * 4, ty = tid >> 4;
    float(*tile)[65] = (float(*)[65])smem;  // 16640 B
    for (int v = bid; v < 3456; v += NBLK) {
      const int z = v / 192;
      const int rem = v - z * 192;
      const int by = rem / 12, bx = rem - by * 12;
      const int c0 = bx * 64, r0 = by * 64;
      if (z >= 16) {  // W cast: [768][768], only 12 row-tiles
        if (by < 12) {
          const float* in = (z == 17 ? Wr : Wl);
          f16_t* outp = (z == 17 ? Wr_h : Wl_h);
          #pragma unroll
          for (int it = 0; it < 4; ++it) {
            const int row = r0 + ty + it * 16;
            const float4 v4 = *(const float4*)&in[(size_t)row * DIM + c0 + x4];
            *(f16x4*)&outp[(size_t)row * DIM + c0 + x4] =
                f16x4{(f16_t)v4.x, (f16_t)v4.y, (f16_t)v4.z, (f16_t)v4.w};
          }
        }
      } else {
        const int n = z & 7;
        const float* in = (z < 8 ? lhs : rhs) + (size_t)n * SEQ * DIM;
        f16_t* fout = (z < 8 ? lhs_f : rhs_f) + (size_t)n * SEQ * DIM;
        float* oh = (z < 8 ? out0 : out1) + (size_t)n * SEQ * 2 * DIM;
        #pragma unroll
        for (int it = 0; it < 4; ++it) {
          const int row = ty + it * 16;
          const float4 v4 =
              *(const float4*)&in[(size_t)(r0 + row) * DIM + c0 + x4];
          *(f16x4*)&fout[(size_t)(r0 + row) * DIM + c0 + x4] =
              f16x4{(f16_t)v4.x, (f16_t)v4.y, (f16_t)v4.z, (f16_t)v4.w};
          *(float4*)&oh[(size_t)(r0 + row) * 2 * DIM + c0 + x4] = v4;
          tile[row][x4 + 0] = v4.x;
          tile[row][x4 + 1] = v4.y;
          tile[row][x4 + 2] = v4.z;
          tile[row][x4 + 3] = v4.w;
        }
        __syncthreads();
        if (z < 8) {
          f16_t* T = lhsT + (size_t)n * SEQ * DIM;  // [DIM][SEQ] fp16
          #pragma unroll
          for (int it = 0; it < 4; ++it) {
            const int cr = ty + it * 16;
            f16x4 o = {(f16_t)tile[x4 + 0][cr], (f16_t)tile[x4 + 1][cr],
                       (f16_t)tile[x4 + 2][cr], (f16_t)tile[x4 + 3][cr]};
            *(f16x4*)&T[(size_t)(c0 + cr) * SEQ + r0 + x4] = o;
          }
        } else {
          unsigned short* T = rhsT + (size_t)n * SEQ * DIM;  // [DIM][SEQ] bf16
          #pragma unroll
          for (int it = 0; it < 4; ++it) {
            const int cr = ty + it * 16;
            u16x4 o = {f2bf(tile[x4 + 0][cr]), f2bf(tile[x4 + 1][cr]),
                       f2bf(tile[x4 + 2][cr]), f2bf(tile[x4 + 3][cr])};
            *(u16x4*)&T[(size_t)(c0 + cr) * SEQ + r0 + x4] = o;
          }
        }
      }
      __syncthreads();  // guard tile reuse across grid-stride iterations
    }
  }
  grid_barrier(sync, 0);

  // ===== phase 1: projection GEMM (batch==XCD, j-outer W reuse) =====
  {
    f16_t* sA = (f16_t*)smem;
    f16_t* sB = sA + 8192;
    const int n = bid & 7;   // XCD
    const int s = bid >> 3;  // 0..95
    const int side = s / 48;
    const int t = s - side * 48;
    const int j = t >> 3, myb = t & 7;  // j outer: W-panel reused 8x
    const int my = n * 8 + myb;
    const f16_t* Ab = (side ? rhs_f : lhs_f) + (size_t)my * 128 * DIM;
    const f16_t* Bb = (side ? Wr_h : Wl_h) + (size_t)j * 128 * DIM;
    f16_t* C = side ? r_f : l_f;

    floatx4 acc[4][4] = {};
    for (int kt = 0; kt < DIM; kt += 64) {
      #pragma unroll
      for (int i = 0; i < 4; ++i) {
        const int ch = i * 4 + wave;
        const int row = ch * 8 + (lane >> 3);
        const size_t g = (size_t)row * DIM + kt + swz;
        async_load16(Ab + g, (char*)sA + ch * 1024);
        async_load16(Bb + g, (char*)sB + ch * 1024);
      }
      __syncthreads();
      #pragma unroll
      for (int ks = 0; ks < 64; ks += 32) {
        f16x8 af[4], bf[4];
        #pragma unroll
        for (int t2 = 0; t2 < 4; ++t2) {
          const int cs = (ks + fq * 8) ^ x7;
          af[t2] = *(const f16x8*)&sA[(wr * 64 + t2 * 16 + fr) * 64 + cs];
          bf[t2] = *(const f16x8*)&sB[(wc * 64 + t2 * 16 + fr) * 64 + cs];
        }
        #pragma unroll
        for (int ti = 0; ti < 4; ++ti)
          #pragma unroll
          for (int tj = 0; tj < 4; ++tj)
            acc[ti][tj] = __builtin_amdgcn_mfma_f32_16x16x32_f16(
                af[ti], bf[tj], acc[ti][tj], 0, 0, 0);
      }
      __syncthreads();
    }
    // C/D layout (m89/m91): col = lane&15, row = (lane>>4)*4 + reg
    const size_t m0 = (size_t)my * 128, n0 = (size_t)j * 128;
    #pragma unroll
    for (int ti = 0; ti < 4; ++ti)
      #pragma unroll
      for (int tj = 0; tj < 4; ++tj) {
        const size_t gm = m0 + wr * 64 + ti * 16 + fq * 4;
        const size_t gn = n0 + wc * 64 + tj * 16 + fr;
        #pragma unroll
        for (int i = 0; i < 4; ++i) {
          // tanh(x) = 1 - 2/(e^{2x}+1)
          const float e = __expf(2.f * acc[ti][tj][i]);
          C[(gm + i) * DIM + gn] =
              (f16_t)(1.f - 2.f * __builtin_amdgcn_rcpf(e + 1.f));
        }
      }
  }
  grid_barrier(sync, 1);

  // ===== phase 2: scores GEMM (512 blocks; batch==XCD, L2-local) =====
  if (bid < 512) {
    f16_t* sA = (f16_t*)smem;
    f16_t* sB = sA + 8192;
    const int z = bid & 7;   // batch == XCD
    const int s = bid >> 3;  // 0..63
    const int my = s >> 3, j = s & 7;
    const f16_t* Ab = l_f + (size_t)z * SEQ * DIM + (size_t)my * 128 * DIM;
    const f16_t* Bb = r_f + (size_t)z * SEQ * DIM + (size_t)j * 128 * DIM;

    floatx4 acc[4][4] = {};
    for (int kt = 0; kt < DIM; kt += 64) {
      #pragma unroll
      for (int i = 0; i < 4; ++i) {
        const int ch = i * 4 + wave;
        const int row = ch * 8 + (lane >> 3);
        const size_t g = (size_t)row * DIM + kt + swz;
        async_load16(Ab + g, (char*)sA + ch * 1024);
        async_load16(Bb + g, (char*)sB + ch * 1024);
      }
      __syncthreads();
      #pragma unroll
      for (int ks = 0; ks < 64; ks += 32) {
        f16x8 af[4], bf[4];
        #pragma unroll
        for (int t2 = 0; t2 < 4; ++t2) {
          const int cs = (ks + fq * 8) ^ x7;
          af[t2] = *(const f16x8*)&sA[(wr * 64 + t2 * 16 + fr) * 64 + cs];
          bf[t2] = *(const f16x8*)&sB[(wc * 64 + t2 * 16 + fr) * 64 + cs];
        }
        #pragma unroll
        for (int ti = 0; ti < 4; ++ti)
          #pragma unroll
          for (int tj = 0; tj < 4; ++tj)
            acc[ti][tj] = __builtin_amdgcn_mfma_f32_16x16x32_f16(
                af[ti], bf[tj], acc[ti][tj], 0, 0, 0);
      }
      __syncthreads();
    }

    const size_t m0 = (size_t)my * 128, n0 = (size_t)j * 128;
    unsigned short* eL = e_l + (size_t)z * SEQ * SEQ;
    f16_t* eT = e_rT + (size_t)z * SEQ * SEQ;

    // row side: e = exp(s - 40) -> bf16 direct + 16-way partial row sums
    #pragma unroll
    for (int ti = 0; ti < 4; ++ti) {
      #pragma unroll
      for (int i = 0; i < 4; ++i) {
        const int rloc = wr * 64 + ti * 16 + fq * 4 + i;
        float sum = 0.f;
        #pragma unroll
        for (int tj = 0; tj < 4; ++tj) {
          const float e = __expf(acc[ti][tj][i] - ROW_SHIFT);
          sum += e;
          eL[(m0 + rloc) * SEQ + n0 + wc * 64 + tj * 16 + fr] = f2bf(e);
        }
        sum += __shfl_xor(sum, 1, 64);
        sum += __shfl_xor(sum, 2, 64);
        sum += __shfl_xor(sum, 4, 64);
        sum += __shfl_xor(sum, 8, 64);
        if (fr == 0)
          rowpart[((size_t)(z * 16 + j * 2 + wc)) * SEQ + m0 + rloc] = sum;
      }
    }
    // col side: e = exp(s*INV_SCALE) -> fp16 via swizzled LDS transpose
    #pragma unroll
    for (int tj = 0; tj < 4; ++tj) {
      const int rp = wc * 64 + tj * 16 + fr;  // e_rT-local row (= score col)
      float sum = 0.f;
      #pragma unroll
      for (int ti = 0; ti < 4; ++ti) {
        #pragma unroll
        for (int i = 0; i < 4; ++i) {
          const float e = __expf(acc[ti][tj][i] * INV_SCALE);
          sum += e;
          const int cp = wr * 64 + ti * 16 + fq * 4 + i;  // e_rT-local col
          *(f16_t*)(smem + rp * 256 + ((cp * 2) ^ ((rp & 7) << 4))) = (f16_t)e;
        }
      }
      sum += __shfl_xor(sum, 16, 64);
      sum += __shfl_xor(sum, 32, 64);
      if (fq == 0)
        colpart[((size_t)(z * 16 + my * 2 + wr)) * SEQ + n0 + rp] = sum;
    }
    __syncthreads();
    // coalesced e_rT store: 16 lanes cover one 256B row segment-pair
    #pragma unroll
    for (int it = 0; it < 8; ++it) {
      const int r = it * 16 + (tid >> 4), chunk = tid & 15;
      const f16x8 v =
          *(const f16x8*)(smem + r * 256 + ((chunk * 16) ^ ((r & 7) << 4)));
      *(f16x8*)&eT[(n0 + r) * SEQ + m0 + chunk * 8] = v;
    }
  }
  grid_barrier(sync, 2);

  // ===== phase 3: apply GEMMs (batch==XCD, j-outer B reuse) =====
  {
    f16_t* sA = (f16_t*)smem;
    f16_t* sB = sA + 8192;
    const int n = bid & 7;   // XCD
    const int s = bid >> 3;  // 0..95
    const int side = s / 48;
    const int t = s - side * 48;
    const int j = t >> 3, my = t & 7;  // j outer: B-panel reused 8x
    const size_t m0 = (size_t)my * 128, n0 = (size_t)j * 128;
    const f16_t* Ab = (side ? e_rT : (const f16_t*)e_l) +
                      (size_t)n * SEQ * SEQ + m0 * SEQ;
    const f16_t* Bb = (side ? lhsT : (const f16_t*)rhsT) +
                      (size_t)n * SEQ * DIM + n0 * SEQ;
    float* C = (side ? out1 : out0) + (size_t)n * SEQ * 2 * DIM + DIM +
               m0 * 2 * DIM + n0;
    const float* pp = (side ? colpart : rowpart) + (size_t)n * 16 * SEQ + m0;

    // finish stats: 1/sum over 16 partials for this block's 128 out rows.
    if (tid < 128) {
      float ssum = 0.f;
      #pragma unroll
      for (int k = 0; k < 16; ++k) ssum += pp[k * SEQ + tid];
      sinv[tid] = 1.f / ssum;
    }

    floatx4 acc[4][4] = {};
    for (int kt = 0; kt < SEQ; kt += 64) {
      #pragma unroll
      for (int i = 0; i < 4; ++i) {
        const int ch = i * 4 + wave;
        const int row = ch * 8 + (lane >> 3);
        const size_t g = (size_t)row * SEQ + kt + swz;
        async_load16(Ab + g, (char*)sA + ch * 1024);
        async_load16(Bb + g, (char*)sB + ch * 1024);
      }
      __syncthreads();
      #pragma unroll
      for (int ks = 0; ks < 64; ks += 32) {
        const int cs = (ks + fq * 8) ^ x7;
        #pragma unroll
        for (int ti = 0; ti < 4; ++ti) {
          const f16_t* pa = &sA[(wr * 64 + ti * 16 + fr) * 64 + cs];
          #pragma unroll
          for (int tj = 0; tj < 4; ++tj) {
            const f16_t* pb = &sB[(wc * 64 + tj * 16 + fr) * 64 + cs];
            if (side == 0)
              acc[ti][tj] = __builtin_amdgcn_mfma_f32_16x16x32_bf16(
                  *(const s16x8*)pa, *(const s16x8*)pb, acc[ti][tj], 0, 0, 0);
            else
              acc[ti][tj] = __builtin_amdgcn_mfma_f32_16x16x32_f16(
                  *(const f16x8*)pa, *(const f16x8*)pb, acc[ti][tj], 0, 0, 0);
          }
        }
      }
      __syncthreads();
    }

    #pragma unroll
    for (int ti = 0; ti < 4; ++ti) {
      const int gm = wr * 64 + ti * 16 + fq * 4;
      const floatx4 iv = *(const floatx4*)&sinv[gm];
      #pragma unroll
      for (int tj = 0; tj < 4; ++tj) {
        const int gn = wc * 64 + tj * 16 + fr;
        #pragma unroll
        for (int i = 0; i < 4; ++i)
          C[(size_t)(gm + i) * (2 * DIM) + gn] = acc[ti][tj][i] * iv[i];
      }
    }
  }
}

// ---------------------------------------------------------------------------
extern "C" void kernel_launch(void* const* d_in, const int* in_sizes, int n_in,
                              void* d_out, int out_size, void* d_ws,
                              size_t ws_size, hipStream_t stream) {
  const float* lhs = (const float*)d_in[0];  // [8][1024][768]
  const float* rhs = (const float*)d_in[1];
  const float* Wl = (const float*)d_in[2];  // [768][768]
  const float* Wr = (const float*)d_in[3];
  float* out0 = (float*)d_out;  // [8][1024][1536]
  float* out1 = out0 + (size_t)NB * SEQ * (2 * DIM);

  // ws layout (stream-ordered lifetime reuse; peak ~85 MB):
  char* ws = (char*)d_ws;
  f16_t* lhsT = (f16_t*)(ws + 0);                           // ->apply
  unsigned short* rhsT = (unsigned short*)(ws + 12582912);  // bf16, ->apply
  f16_t* l_f = (f16_t*)(ws + 25165824);                     // dead after scores
  f16_t* r_f = (f16_t*)(ws + 37748736);                     // dead after scores
  f16_t* lhs_f = (f16_t*)(ws + 50331648);                   // dead after proj
  f16_t* rhs_f = (f16_t*)(ws + 62914560);                   // dead after proj
  f16_t* Wl_h = (f16_t*)(ws + 75497472);                    // dead after proj
  f16_t* Wr_h = (f16_t*)(ws + 76677120);
  unsigned short* e_l = (unsigned short*)(ws + 50331648);  // overlays lhs_f+
  f16_t* e_rT = (f16_t*)(ws + 67108864);                   // overlays rhs_f+W
  float* rowpart = (float*)(ws + 83886080);                // 512KB (16-way)
  float* colpart = (float*)(ws + 84410368);                // 512KB -> 84934656
  unsigned* sync = (unsigned*)(ws + 84934656);             // 3x{cnt,flag}

  hipMemsetAsync(sync, 0, 64, stream);
  mega<<<NBLK, 256, 0, stream>>>(lhs, rhs, Wl, Wr, lhs_f, rhs_f, Wl_h, Wr_h,
                                 lhsT, rhsT, l_f, r_f, e_l, e_rT, rowpart,
                                 colpart, out0, out1, sync);
}